// Round 15
// baseline (143.934 us; speedup 1.0000x reference)
//
#include <hip/hip_runtime.h>
#include <hip/hip_bf16.h>

#define N_NODES 50000
#define N_EDGES 800000
#define D_IN 96
#define D_OUT 128
#define CAP 64
#define CAPP 72             // bkt row pitch u16: lo slots [0,32), hi [32,64),
                            // [64,72) pad; 144 B = 9*16 B (b128-aligned rows)
#define HALF_CAP 32         // per-src-half bucket capacity (lambda=8, P(ovf)~5e-8)
#define N_HALF 25000        // src-half boundary: xh rows [0,25K) = 4.8 MB

// Deterministic partition (R9-proven): bins of 64 nodes, fixed 24-slot
// 128B-aligned sub-chunks, zero device atomics, zero memset. NEW (R14
// lesson): cells store lo-src edges from the front, hi-src from the back,
// so K2 can gather each src-half in a separate temporal pass whose working
// set (4.8 MB) approaches XCD-L2 size. Monolithic 192B xh rows restored
// (64B-line-aligned; the 96B feature-split cost +14% line overfetch).
#define NPB 64
#define N_BINS ((N_NODES + NPB - 1) / NPB)          // 782
#define CAP_SUB 24          // edges per cell; lambda=4 -> P(ovf) ~1e-13/cell
#define CAP_STRIDE 32       // u32 stride per cell = 128 B (line-aligned)
#define PART_EPB 3125
#define PART_BLOCKS (N_EDGES / PART_EPB)            // 256 exactly
#define PART_SLOTS 13                               // ceil(3125/256)

#define CONV_THREADS (N_NODES * 12)                 // 600000
#define CONV_BLOCKS ((CONV_THREADS + 255) / 256)    // 2344
#define WCONV_BLOCKS 12                             // 128*24 = 3072 tasks

#define AG_BLOCKS N_BINS                            // 782
#define AH_PITCH 104        // u16/row (96+8 pad); 208 B = 13*16 B

typedef unsigned short u16;
typedef __attribute__((ext_vector_type(8))) short short8;   // 8 x bf16
typedef __attribute__((ext_vector_type(4))) float f32x4;

__device__ __forceinline__ u16 f2bf(float f) {
    unsigned u = __float_as_uint(f);
    unsigned r = (u + 0x7FFFu + ((u >> 16) & 1u)) >> 16;   // RNE
    return (u16)r;
}
__device__ __forceinline__ float bf2f(u16 h) {
    return __uint_as_float(((unsigned)h) << 16);
}

// 8/4/1 gather-accumulate walk over bkt slots [e0,e1) of row brow,
// gathering xh rows at chunk c8. e0 must be a multiple of 8 (b128 align).
#define WALK(e0, e1, brow, xbase, c8, acc)                                     \
    {                                                                          \
        int e = (e0);                                                          \
        for (; e + 8 <= (e1); e += 8) {                                        \
            short8 id = *(const short8*)((brow) + e);                          \
            short8 v[8];                                                       \
            _Pragma("unroll")                                                  \
            for (int q = 0; q < 8; q++) {                                      \
                unsigned s = (u16)id[q];                                       \
                v[q] = *(const short8*)((xbase) + s * (unsigned)D_IN + (c8) * 8u); \
            }                                                                  \
            _Pragma("unroll")                                                  \
            for (int q = 0; q < 8; q++)                                        \
                _Pragma("unroll")                                              \
                for (int i = 0; i < 8; i++) (acc)[i] += bf2f((u16)v[q][i]);    \
        }                                                                      \
        if (e + 4 <= (e1)) {                                                   \
            unsigned s0 = (brow)[e + 0];                                       \
            unsigned s1 = (brow)[e + 1];                                       \
            unsigned s2 = (brow)[e + 2];                                       \
            unsigned s3 = (brow)[e + 3];                                       \
            short8 v0 = *(const short8*)((xbase) + s0 * (unsigned)D_IN + (c8) * 8u); \
            short8 v1 = *(const short8*)((xbase) + s1 * (unsigned)D_IN + (c8) * 8u); \
            short8 v2 = *(const short8*)((xbase) + s2 * (unsigned)D_IN + (c8) * 8u); \
            short8 v3 = *(const short8*)((xbase) + s3 * (unsigned)D_IN + (c8) * 8u); \
            _Pragma("unroll")                                                  \
            for (int i = 0; i < 8; i++)                                        \
                (acc)[i] += bf2f((u16)v0[i]) + bf2f((u16)v1[i])                \
                          + bf2f((u16)v2[i]) + bf2f((u16)v3[i]);               \
            e += 4;                                                            \
        }                                                                      \
        for (; e < (e1); e++) {                                                \
            unsigned s = (brow)[e];                                            \
            short8 v = *(const short8*)((xbase) + s * (unsigned)D_IN + (c8) * 8u); \
            _Pragma("unroll")                                                  \
            for (int i = 0; i < 8; i++) (acc)[i] += bf2f((u16)v[i]);           \
        }                                                                      \
    }

// ---------------------------------------------------------------------------
// K1: heterogeneous grid.
//   [0, PART_BLOCKS): partition with src-half separation. Per-bin LDS
//     histograms for lo (src<25K) and hi; packed u16 counts (lo<<8|hi);
//     lo edges scattered to cell front, hi to cell back. No device atomics.
//   [.., +CONV_BLOCKS): xh = bf16(x), MONOLITHIC 192B rows (line-aligned).
//   [.., +WCONV_BLOCKS): Wfrag = bf16 B-fragment-layout [Wl|Wr].
// ---------------------------------------------------------------------------
__global__ __launch_bounds__(256) void sage_part_conv(
    const int* __restrict__ src,
    const int* __restrict__ dst,
    const float* __restrict__ x,
    const float* __restrict__ Wl,
    const float* __restrict__ Wr,
    u16* __restrict__ cnts,
    unsigned* __restrict__ binbuf,
    u16* __restrict__ xh,
    u16* __restrict__ Wfrag)
{
    __shared__ unsigned hist_lo[N_BINS], hist_hi[N_BINS];
    __shared__ unsigned cur_lo[N_BINS],  cur_hi[N_BINS];

    const int b = blockIdx.x;
    const int tid = (int)threadIdx.x;

    if (b < PART_BLOCKS) {
        for (int i = tid; i < N_BINS; i += 256) {
            hist_lo[i] = 0u; hist_hi[i] = 0u; cur_lo[i] = 0u; cur_hi[i] = 0u;
        }
        __syncthreads();

        const int ebase = b * PART_EPB;
        const int e0 = ebase + tid;
        int d[PART_SLOTS], s[PART_SLOTS];
#pragma unroll
        for (int i = 0; i < PART_SLOTS; i++) {      // coalesced batch loads
            int valid = (tid + i * 256) < PART_EPB;
            int e = valid ? (e0 + i * 256) : ebase;
            d[i] = dst[e];
            s[i] = src[e];
        }
#pragma unroll
        for (int i = 0; i < PART_SLOTS; i++) {
            if ((tid + i * 256) < PART_EPB) {
                int bn = d[i] >> 6;
                if (s[i] < N_HALF) atomicAdd(&hist_lo[bn], 1u);  // LDS atomic
                else               atomicAdd(&hist_hi[bn], 1u);
            }
        }
        __syncthreads();
        for (int i = tid; i < N_BINS; i += 256) {   // packed plain-store counts
            unsigned hl = hist_lo[i] > CAP_SUB ? CAP_SUB : hist_lo[i];
            unsigned hh = hist_hi[i] > CAP_SUB ? CAP_SUB : hist_hi[i];
            cnts[(size_t)i * PART_BLOCKS + b] = (u16)((hl << 8) | hh);
        }
#pragma unroll
        for (int i = 0; i < PART_SLOTS; i++) {
            if ((tid + i * 256) < PART_EPB) {
                int bn = d[i] >> 6;
                unsigned dl = (unsigned)(d[i] & 63);
                unsigned w = (dl << 16) | (unsigned)s[i];
                unsigned cell = ((unsigned)bn * PART_BLOCKS + (unsigned)b)
                                * CAP_STRIDE;
                if (s[i] < N_HALF) {                // lo: front of cell
                    unsigned loc = atomicAdd(&cur_lo[bn], 1u);
                    if (loc < CAP_SUB) binbuf[cell + loc] = w;
                } else {                            // hi: back of cell
                    unsigned loc = atomicAdd(&cur_hi[bn], 1u);
                    if (loc < CAP_SUB) binbuf[cell + (CAP_SUB - 1u - loc)] = w;
                }
            }
        }
    } else if (b < PART_BLOCKS + CONV_BLOCKS) {
        unsigned t = (unsigned)(b - PART_BLOCKS) * 256u + threadIdx.x;
        if (t >= (unsigned)CONV_THREADS) return;
        unsigned n = t / 12u;
        unsigned c8 = t - n * 12u;
        const float* p = x + (size_t)n * D_IN + c8 * 8u;
        short8 v;
#pragma unroll
        for (int i = 0; i < 8; i++) v[i] = (short)f2bf(p[i]);
        *(short8*)(xh + (size_t)n * D_IN + c8 * 8u) = v;
    } else {
        // W -> bf16 fragments: 128 j x 24 chunks (12 Wl + 12 Wr)
        int idx = (b - PART_BLOCKS - CONV_BLOCKS) * 256 + tid;   // < 3072
        int j = idx / 24;
        int c8 = idx - j * 24;
        int kc = c8 >> 2;
        int quad = c8 & 3;
        const float* wsrc = (c8 < 12) ? (Wl + (size_t)j * D_IN + c8 * 8)
                                      : (Wr + (size_t)j * D_IN + (c8 - 12) * 8);
        int jt = j >> 4;
        int col = j & 15;
        short8 v;
#pragma unroll
        for (int i = 0; i < 8; i++) v[i] = (short)f2bf(wsrc[i]);
        *(short8*)(Wfrag + (((jt * 6 + kc) * 64) + col + 16 * quad) * 8) = v;
    }
}

// ---------------------------------------------------------------------------
// K2 (512-thread, src-half temporally-phased gather, shfl merge):
// block j owns nodes [j*64,+64).
// R14 post-mortem: feature-split raised FETCH (96B rows not line-aligned)
// and never separated phases temporally. This version: bucket rows hold lo
// edges in slots [0,32), hi in [32,64); phase A pass 0 walks ONLY lo (all
// lanes gather xh rows [0,25K) = 4.8MB), pass 1 ONLY hi — wave-level
// temporal separation by construction. Pair-split within each pass at an
// 8-aligned mid (R11 alignment lesson); __shfl_xor(acc,1) merge (R13).
// ---------------------------------------------------------------------------
__global__ __launch_bounds__(512) void sage_agg_gemm(
    const u16* __restrict__ xh,
    const u16* __restrict__ cnts,
    const unsigned* __restrict__ binbuf,
    const u16* __restrict__ Wfrag,
    const float* __restrict__ bl,
    float* __restrict__ out)
{
    __shared__ __align__(16) u16 bkt[NPB * CAPP];   // 9216 B
    __shared__ unsigned cnt_lo_l[NPB], cnt_hi_l[NPB];
    __shared__ __align__(16) u16 Ah[NPB * AH_PITCH];// 13312 B (total ~23 KB)

    const int j = blockIdx.x;                       // bin == block
    const int tid = (int)threadIdx.x;
    const int n0 = j * NPB;

    if (tid < NPB) { cnt_lo_l[tid] = 0u; cnt_hi_l[tid] = 0u; }
    __syncthreads();

    // ---- prologue: threads 0-255 ingest cells (thread t = pblock t) ------
    if (tid < PART_BLOCKS) {
        unsigned pk = cnts[(size_t)j * PART_BLOCKS + tid];
        unsigned cl = (pk >> 8) & 0xFFu; if (cl > CAP_SUB) cl = CAP_SUB;
        unsigned ch = pk & 0xFFu;        if (ch > CAP_SUB) ch = CAP_SUB;
        const uint4* sc = (const uint4*)(binbuf
                          + ((size_t)j * PART_BLOCKS + tid) * CAP_STRIDE);
        uint4 q0 = {0,0,0,0}, q1 = {0,0,0,0}, q2 = {0,0,0,0};
        uint4 q3 = {0,0,0,0}, q4 = {0,0,0,0}, q5 = {0,0,0,0};
        if (cl > 0  || ch > 20) q0 = sc[0];         // word group [4i,4i+4)
        if (cl > 4  || ch > 16) q1 = sc[1];         // needed iff it meets
        if (cl > 8  || ch > 12) q2 = sc[2];         // [0,cl) u [24-ch,24)
        if (cl > 12 || ch > 8)  q3 = sc[3];
        if (cl > 16 || ch > 4)  q4 = sc[4];
        if (cl > 20 || ch > 0)  q5 = sc[5];
        unsigned buf[CAP_SUB];
        buf[0]=q0.x;  buf[1]=q0.y;  buf[2]=q0.z;  buf[3]=q0.w;
        buf[4]=q1.x;  buf[5]=q1.y;  buf[6]=q1.z;  buf[7]=q1.w;
        buf[8]=q2.x;  buf[9]=q2.y;  buf[10]=q2.z; buf[11]=q2.w;
        buf[12]=q3.x; buf[13]=q3.y; buf[14]=q3.z; buf[15]=q3.w;
        buf[16]=q4.x; buf[17]=q4.y; buf[18]=q4.z; buf[19]=q4.w;
        buf[20]=q5.x; buf[21]=q5.y; buf[22]=q5.z; buf[23]=q5.w;
#pragma unroll
        for (int e = 0; e < CAP_SUB; e++) {         // static indices (rule #20)
            bool is_lo = (unsigned)e < cl;
            bool is_hi = (unsigned)e >= (CAP_SUB - ch);
            if (is_lo) {
                unsigned w = buf[e];
                unsigned r = w >> 16;
                unsigned p = atomicAdd(&cnt_lo_l[r], 1u);
                if (p < HALF_CAP) bkt[r * CAPP + p] = (u16)(w & 0xFFFFu);
            } else if (is_hi) {
                unsigned w = buf[e];
                unsigned r = w >> 16;
                unsigned p = atomicAdd(&cnt_hi_l[r], 1u);
                if (p < HALF_CAP) bkt[r * CAPP + HALF_CAP + p] = (u16)(w & 0xFFFFu);
            }
        }
    }
    __syncthreads();

    // ---- phase A: pass 0 = lo srcs only (4.8MB WS), pass 1 = hi srcs -----
#pragma unroll
    for (int rep = 0; rep < 3; rep++) {
        int pair = rep * 256 + (tid >> 1);   // 0..767
        int m = pair / 12;                   // node 0..63
        int c8 = pair - m * 12;              // chunk 0..11
        int half = tid & 1;
        int n = n0 + m;

        float acc[8];
#pragma unroll
        for (int i = 0; i < 8; i++) acc[i] = 0.0f;
        int cl = 0, ch = 0;

        if (n < N_NODES) {
            cl = (int)cnt_lo_l[m]; if (cl > HALF_CAP) cl = HALF_CAP;
            ch = (int)cnt_hi_l[m]; if (ch > HALF_CAP) ch = HALF_CAP;
            const u16* brow = bkt + m * CAPP;
            {   // pass 0: lo region [0, cl); 8-aligned pair split
                int mid = ((cl >> 1) + 4) & ~7;     // provably <= cl
                int es = half ? mid : 0;
                int ee = half ? cl : mid;
                WALK(es, ee, brow, xh, c8, acc)
            }
            {   // pass 1: hi region [32, 32+ch); base 32 is 8-aligned
                int mid = ((ch >> 1) + 4) & ~7;     // provably <= ch
                int es = HALF_CAP + (half ? mid : 0);
                int ee = HALF_CAP + (half ? ch : mid);
                WALK(es, ee, brow, xh, c8, acc)
            }
        }

        // merge halves across adjacent lanes (convergent)
#pragma unroll
        for (int i = 0; i < 8; i++)
            acc[i] += __shfl_xor(acc[i], 1);

        if (half == 0) {                     // even lane finalizes + writes
            float invd = (n < N_NODES)
                       ? 1.0f / fmaxf((float)(cl + ch), 1.0f) : 0.0f;
            short8 o;
#pragma unroll
            for (int i = 0; i < 8; i++)
                o[i] = (short)f2bf(acc[i] * invd);
            *(short8*)(Ah + m * AH_PITCH + c8 * 8) = o;
        }
    }
    __syncthreads();

    // ---- phase B: 8 waves; wave w = (tile w&3, jt-quad w>>2) ----
    const int wave = tid >> 6;
    const int lane = tid & 63;
    const int m16 = lane & 15;
    const int quad = lane >> 4;
    const int tile = wave & 3;
    const int jt0 = (wave >> 2) * 4;
    const int tilebase = n0 + tile * 16;
    if (tilebase >= N_NODES) return;         // all barriers already passed

    int nn = tilebase + m16;
    nn = nn < N_NODES ? nn : N_NODES - 1;    // clamp A-row src (store guarded)

    const u16* arow = Ah + (tile * 16 + m16) * AH_PITCH + quad * 8;
    const u16* xrow = xh + (size_t)nn * D_IN + quad * 8;
    short8 a[6];
#pragma unroll
    for (int kc = 0; kc < 3; kc++) a[kc]     = *(const short8*)(arow + kc * 32);
#pragma unroll
    for (int kc = 0; kc < 3; kc++) a[3 + kc] = *(const short8*)(xrow + kc * 32);

#pragma unroll
    for (int jt = 0; jt < 4; jt++) {
        const int jtt = jt0 + jt;
        f32x4 acc = {0.0f, 0.0f, 0.0f, 0.0f};
#pragma unroll
        for (int kc = 0; kc < 6; kc++) {
            short8 bfrag = *(const short8*)(Wfrag + ((jtt * 6 + kc) * 64 + lane) * 8);
            acc = __builtin_amdgcn_mfma_f32_16x16x32_bf16(a[kc], bfrag, acc, 0, 0, 0);
        }
        const int jj = jtt * 16 + m16;       // col = lane&15
        const float bj = bl[jj];
#pragma unroll
        for (int r = 0; r < 4; r++) {
            int row = quad * 4 + r;
            int n = tilebase + row;
            if (n < N_NODES)
                out[(size_t)n * D_OUT + jj] = fmaxf(acc[r] + bj, 0.0f);
        }
    }
}

extern "C" void kernel_launch(void* const* d_in, const int* in_sizes, int n_in,
                              void* d_out, int out_size, void* d_ws, size_t ws_size,
                              hipStream_t stream) {
    const float* x   = (const float*)d_in[0];
    const int* eidx  = (const int*)d_in[1];
    const float* Wl  = (const float*)d_in[2];
    const float* bl  = (const float*)d_in[3];
    const float* Wr  = (const float*)d_in[4];
    float* out = (float*)d_out;

    const int* src = eidx;                // edge_index[0]
    const int* dst = eidx + N_EDGES;      // edge_index[1]

    // ws layout (byte offsets) — no zero-init needed anywhere:
    //   binbuf    0          25,624,576 B (782*256*32 u32, 128 B cells)
    //   cnts      25,624,576    400,384 B (782*256 u16 packed lo<<8|hi)
    //   xh        26,025,088  9,600,000 B (bf16, monolithic 192 B rows)
    //   Wfrag     35,625,088     49,152 B
    char* ws = (char*)d_ws;
    unsigned* binbuf = (unsigned*)ws;
    u16*      cnts   = (u16*)(ws + 25624576);
    u16*      xh     = (u16*)(ws + 26025088);
    u16*      Wfrag  = (u16*)(ws + 35625088);

    {
        dim3 grid(PART_BLOCKS + CONV_BLOCKS + WCONV_BLOCKS);   // 2612
        sage_part_conv<<<grid, 256, 0, stream>>>(src, dst, x, Wl, Wr,
                                                 cnts, binbuf, xh, Wfrag);
    }
    {
        dim3 grid(AG_BLOCKS);                                  // 782
        sage_agg_gemm<<<grid, 512, 0, stream>>>(xh, cnts, binbuf,
                                                Wfrag, bl, out);
    }
}

// Round 16
// 129.234 us; speedup vs baseline: 1.1137x; 1.1137x over previous
//
#include <hip/hip_runtime.h>
#include <hip/hip_bf16.h>

#define N_NODES 50000
#define N_EDGES 800000
#define D_IN 96
#define D_OUT 128
#define CAP 64              // deg ~ Poisson(16); P(deg>=64) ~ e^-41 -> no drops
#define CAPP 72             // bkt row pitch (u16): 144 B = 9*16 B (b128-aligned)

// R16: NPB 64 -> 50 so AG grid = 1000 = 3*256+232 (tail excess 24% -> 2%).
// R12-R15 lesson: every internal phase-A restructure hit the same ~45us wall;
// 782 = 3*256+14 grid left 95% of the machine idle during the 4th round.
#define NPB 50                                      // nodes per bin/agg block
#define N_BINS ((N_NODES + NPB - 1) / NPB)          // 1000 exactly
#define CAP_SUB 24          // edges per (pblock,bin); lambda=3.1 -> P(ovf)~0
#define CAP_STRIDE 32       // u32 stride per cell = 128 B (line-aligned)
#define PART_EPB 3125
#define PART_BLOCKS (N_EDGES / PART_EPB)            // 256 exactly
#define PART_SLOTS 13                               // ceil(3125/256)

#define CONV_THREADS (N_NODES * 12)                 // 600000
#define CONV_BLOCKS ((CONV_THREADS + 255) / 256)    // 2344
#define WCONV_BLOCKS 12                             // 128*24 = 3072 tasks

#define AG_BLOCKS N_BINS                            // 1000
#define AH_PITCH 104        // u16/row (96+8 pad); 208 B = 13*16 B

typedef unsigned short u16;
typedef __attribute__((ext_vector_type(8))) short short8;   // 8 x bf16
typedef __attribute__((ext_vector_type(4))) float f32x4;

__device__ __forceinline__ u16 f2bf(float f) {
    unsigned u = __float_as_uint(f);
    unsigned r = (u + 0x7FFFu + ((u >> 16) & 1u)) >> 16;   // RNE
    return (u16)r;
}
__device__ __forceinline__ float bf2f(u16 h) {
    return __uint_as_float(((unsigned)h) << 16);
}

// ---------------------------------------------------------------------------
// K1: heterogeneous grid (structure R9-proven; single histogram again —
// R15's src-half split regressed and is reverted).
//   [0, PART_BLOCKS): deterministic partition, no device atomics.
//   [.., +CONV_BLOCKS): xh = bf16(x), monolithic 192 B rows (line-aligned).
//   [.., +WCONV_BLOCKS): Wfrag = bf16 B-fragment-layout [Wl|Wr].
// ---------------------------------------------------------------------------
__global__ __launch_bounds__(256) void sage_part_conv(
    const int* __restrict__ src,
    const int* __restrict__ dst,
    const float* __restrict__ x,
    const float* __restrict__ Wl,
    const float* __restrict__ Wr,
    u16* __restrict__ cnts,
    unsigned* __restrict__ binbuf,
    u16* __restrict__ xh,
    u16* __restrict__ Wfrag)
{
    __shared__ unsigned hist[N_BINS];
    __shared__ unsigned cur[N_BINS];

    const int b = blockIdx.x;
    const int tid = (int)threadIdx.x;

    if (b < PART_BLOCKS) {
        for (int i = tid; i < N_BINS; i += 256) { hist[i] = 0u; cur[i] = 0u; }
        __syncthreads();

        const int ebase = b * PART_EPB;
        const int e0 = ebase + tid;
        int d[PART_SLOTS], s[PART_SLOTS];
#pragma unroll
        for (int i = 0; i < PART_SLOTS; i++) {      // coalesced batch loads
            int valid = (tid + i * 256) < PART_EPB;
            int e = valid ? (e0 + i * 256) : ebase;
            d[i] = dst[e];
            s[i] = src[e];
        }
#pragma unroll
        for (int i = 0; i < PART_SLOTS; i++) {
            if ((tid + i * 256) < PART_EPB)
                atomicAdd(&hist[d[i] / NPB], 1u);   // LDS atomic (magic-mul /50)
        }
        __syncthreads();
        for (int i = tid; i < N_BINS; i += 256)     // plain-store counts
            cnts[(size_t)i * PART_BLOCKS + b] = (u16)hist[i];
#pragma unroll
        for (int i = 0; i < PART_SLOTS; i++) {
            if ((tid + i * 256) < PART_EPB) {
                int bn = d[i] / NPB;
                unsigned dl = (unsigned)(d[i] - bn * NPB);   // < 50
                unsigned loc = atomicAdd(&cur[bn], 1u);      // LDS atomic
                if (loc < CAP_SUB)                  // P(ovf) ~ 0 at lambda=3.1
                    binbuf[((unsigned)bn * PART_BLOCKS + (unsigned)b) * CAP_STRIDE
                           + loc] = (dl << 16) | (unsigned)s[i];
            }
        }
    } else if (b < PART_BLOCKS + CONV_BLOCKS) {
        unsigned t = (unsigned)(b - PART_BLOCKS) * 256u + threadIdx.x;
        if (t >= (unsigned)CONV_THREADS) return;
        unsigned n = t / 12u;
        unsigned c8 = t - n * 12u;
        const float* p = x + (size_t)n * D_IN + c8 * 8u;
        short8 v;
#pragma unroll
        for (int i = 0; i < 8; i++) v[i] = (short)f2bf(p[i]);
        *(short8*)(xh + (size_t)n * D_IN + c8 * 8u) = v;
    } else {
        // W -> bf16 fragments: 128 j x 24 chunks (12 Wl + 12 Wr)
        int idx = (b - PART_BLOCKS - CONV_BLOCKS) * 256 + tid;   // < 3072
        int j = idx / 24;
        int c8 = idx - j * 24;
        int kc = c8 >> 2;
        int quad = c8 & 3;
        const float* wsrc = (c8 < 12) ? (Wl + (size_t)j * D_IN + c8 * 8)
                                      : (Wr + (size_t)j * D_IN + (c8 - 12) * 8);
        int jt = j >> 4;
        int col = j & 15;
        short8 v;
#pragma unroll
        for (int i = 0; i < 8; i++) v[i] = (short)f2bf(wsrc[i]);
        *(short8*)(Wfrag + (((jt * 6 + kc) * 64) + col + 16 * quad) * 8) = v;
    }
}

// ---------------------------------------------------------------------------
// K2 (512-thread, R13-structure phase A, balanced 1000-block grid):
// block j owns nodes [j*50, +50).
// Phase A: pair=(m,c8) on adjacent lanes, 8-aligned edge split (R11
// alignment lesson), __shfl_xor(acc,1) merge (R13 — best measured).
// Masked pairs (>=600) and rows >=50 guarded everywhere (NPB=50 < 64).
// Phase B: 8 waves; wave w = tile (w&3), jt-quad (w>>2); tile 3 rows 48-63
// masked to rows < 50.
// ---------------------------------------------------------------------------
__global__ __launch_bounds__(512) void sage_agg_gemm(
    const u16* __restrict__ xh,
    const u16* __restrict__ cnts,
    const unsigned* __restrict__ binbuf,
    const u16* __restrict__ Wfrag,
    const float* __restrict__ bl,
    float* __restrict__ out)
{
    __shared__ __align__(16) u16 bkt[NPB * CAPP];   // 7200 B (padded rows)
    __shared__ unsigned cnt_l[NPB];                 // 200 B
    __shared__ __align__(16) u16 Ah[NPB * AH_PITCH];// 10400 B (total ~17.8 KB)

    const int j = blockIdx.x;                       // bin == block
    const int tid = (int)threadIdx.x;
    const int n0 = j * NPB;

    if (tid < NPB) cnt_l[tid] = 0u;
    __syncthreads();

    // ---- prologue: threads 0-255 ingest cells (thread t = pblock t) ------
    if (tid < PART_BLOCKS) {
        unsigned cnt_t = cnts[(size_t)j * PART_BLOCKS + tid];
        const uint4* sc = (const uint4*)(binbuf
                          + ((size_t)j * PART_BLOCKS + tid) * CAP_STRIDE);
        unsigned lim = cnt_t < CAP_SUB ? cnt_t : CAP_SUB;
        uint4 q0 = {0,0,0,0}, q1 = {0,0,0,0}, q2 = {0,0,0,0};
        uint4 q3 = {0,0,0,0}, q4 = {0,0,0,0}, q5 = {0,0,0,0};
        if (lim > 0)  q0 = sc[0];                   // exec-masked loads
        if (lim > 4)  q1 = sc[1];
        if (lim > 8)  q2 = sc[2];
        if (lim > 12) q3 = sc[3];
        if (lim > 16) q4 = sc[4];
        if (lim > 20) q5 = sc[5];
        unsigned buf[CAP_SUB];
        buf[0]=q0.x;  buf[1]=q0.y;  buf[2]=q0.z;  buf[3]=q0.w;
        buf[4]=q1.x;  buf[5]=q1.y;  buf[6]=q1.z;  buf[7]=q1.w;
        buf[8]=q2.x;  buf[9]=q2.y;  buf[10]=q2.z; buf[11]=q2.w;
        buf[12]=q3.x; buf[13]=q3.y; buf[14]=q3.z; buf[15]=q3.w;
        buf[16]=q4.x; buf[17]=q4.y; buf[18]=q4.z; buf[19]=q4.w;
        buf[20]=q5.x; buf[21]=q5.y; buf[22]=q5.z; buf[23]=q5.w;
#pragma unroll
        for (int e = 0; e < CAP_SUB; e++) {         // static indices (rule #20)
            if ((unsigned)e < lim) {
                unsigned w = buf[e];
                unsigned r = w >> 16;               // local node, < 50
                unsigned p = atomicAdd(&cnt_l[r], 1u);
                if (p < CAP) bkt[r * CAPP + p] = (u16)(w & 0xFFFFu);
            }
        }
    }
    __syncthreads();

    // ---- phase A: pair=(m,c8) on adjacent lanes; 600 pairs over 3 reps ---
#pragma unroll
    for (int rep = 0; rep < 3; rep++) {
        int pair = rep * 256 + (tid >> 1);   // 0..767 (>=600 masked)
        int m = pair / 12;                   // node 0..63 (>=50 masked)
        int c8 = pair - m * 12;              // chunk 0..11
        int half = tid & 1;

        float acc[8];
#pragma unroll
        for (int i = 0; i < 8; i++) acc[i] = 0.0f;
        int deg = 0;

        if (m < NPB) {                       // masked tasks skip entirely
            deg = (int)cnt_l[m];
            int dc = deg < CAP ? deg : CAP;
            // 8-ALIGNED split (ds_read_b128 needs 16B-aligned LDS addr):
            // mid <= dc provably (dc>=8 -> dc/2+4 <= dc; dc<8 -> mid=0).
            int mid = ((dc >> 1) + 4) & ~7;
            int e_lo = half ? mid : 0;
            int e_hi = half ? dc : mid;
            const u16* brow = bkt + m * CAPP;       // LDS (144B-pitch rows)
            int e = e_lo;                           // multiple of 8
            for (; e + 8 <= e_hi; e += 8) {
                short8 id = *(const short8*)(brow + e);   // aligned LDS b128
                short8 v[8];
#pragma unroll
                for (int q = 0; q < 8; q++) {
                    unsigned s = (u16)id[q];
                    v[q] = *(const short8*)(xh + s * (unsigned)D_IN + c8 * 8u);
                }
#pragma unroll
                for (int q = 0; q < 8; q++)
#pragma unroll
                    for (int i = 0; i < 8; i++) acc[i] += bf2f((u16)v[q][i]);
            }
            if (e + 4 <= e_hi) {                    // scalar u16 index reads
                unsigned s0 = brow[e + 0];
                unsigned s1 = brow[e + 1];
                unsigned s2 = brow[e + 2];
                unsigned s3 = brow[e + 3];
                short8 v0 = *(const short8*)(xh + s0 * (unsigned)D_IN + c8 * 8u);
                short8 v1 = *(const short8*)(xh + s1 * (unsigned)D_IN + c8 * 8u);
                short8 v2 = *(const short8*)(xh + s2 * (unsigned)D_IN + c8 * 8u);
                short8 v3 = *(const short8*)(xh + s3 * (unsigned)D_IN + c8 * 8u);
#pragma unroll
                for (int i = 0; i < 8; i++)
                    acc[i] += bf2f((u16)v0[i]) + bf2f((u16)v1[i])
                            + bf2f((u16)v2[i]) + bf2f((u16)v3[i]);
                e += 4;
            }
            for (; e < e_hi; e++) {
                unsigned s = brow[e];
                short8 v = *(const short8*)(xh + s * (unsigned)D_IN + c8 * 8u);
#pragma unroll
                for (int i = 0; i < 8; i++) acc[i] += bf2f((u16)v[i]);
            }
        }

        // merge halves across adjacent lanes (convergent: all lanes execute)
#pragma unroll
        for (int i = 0; i < 8; i++)
            acc[i] += __shfl_xor(acc[i], 1);

        if (half == 0 && m < NPB) {          // even lane finalizes + writes
            float invd = 1.0f / fmaxf((float)deg, 1.0f);
            short8 o;
#pragma unroll
            for (int i = 0; i < 8; i++)
                o[i] = (short)f2bf(acc[i] * invd);
            *(short8*)(Ah + m * AH_PITCH + c8 * 8) = o;
        }
    }
    __syncthreads();

    // ---- phase B: 8 waves; wave w = (tile w&3, jt-quad w>>2) ----
    const int wave = tid >> 6;
    const int lane = tid & 63;
    const int m16 = lane & 15;
    const int quad = lane >> 4;
    const int tile = wave & 3;
    const int jt0 = (wave >> 2) * 4;

    int mrow = tile * 16 + m16;              // 0..63
    int mclamp = mrow < NPB ? mrow : NPB - 1;       // clamp LDS/x sources
    int nn = n0 + mclamp;                    // < N_NODES by construction

    const u16* arow = Ah + mclamp * AH_PITCH + quad * 8;
    const u16* xrow = xh + (size_t)nn * D_IN + quad * 8;
    short8 a[6];
#pragma unroll
    for (int kc = 0; kc < 3; kc++) a[kc]     = *(const short8*)(arow + kc * 32);
#pragma unroll
    for (int kc = 0; kc < 3; kc++) a[3 + kc] = *(const short8*)(xrow + kc * 32);

#pragma unroll
    for (int jt = 0; jt < 4; jt++) {
        const int jtt = jt0 + jt;
        f32x4 acc = {0.0f, 0.0f, 0.0f, 0.0f};
#pragma unroll
        for (int kc = 0; kc < 6; kc++) {
            short8 bfrag = *(const short8*)(Wfrag + ((jtt * 6 + kc) * 64 + lane) * 8);
            acc = __builtin_amdgcn_mfma_f32_16x16x32_bf16(a[kc], bfrag, acc, 0, 0, 0);
        }
        const int jj = jtt * 16 + m16;       // col = lane&15
        const float bj = bl[jj];
#pragma unroll
        for (int r = 0; r < 4; r++) {
            int row = tile * 16 + quad * 4 + r;     // 0..63
            if (row < NPB)                   // rows >= 50 belong to next bin
                out[(size_t)(n0 + row) * D_OUT + jj] = fmaxf(acc[r] + bj, 0.0f);
        }
    }
}

extern "C" void kernel_launch(void* const* d_in, const int* in_sizes, int n_in,
                              void* d_out, int out_size, void* d_ws, size_t ws_size,
                              hipStream_t stream) {
    const float* x   = (const float*)d_in[0];
    const int* eidx  = (const int*)d_in[1];
    const float* Wl  = (const float*)d_in[2];
    const float* bl  = (const float*)d_in[3];
    const float* Wr  = (const float*)d_in[4];
    float* out = (float*)d_out;

    const int* src = eidx;                // edge_index[0]
    const int* dst = eidx + N_EDGES;      // edge_index[1]

    // ws layout (byte offsets) — no zero-init needed anywhere:
    //   binbuf    0          32,768,000 B (1000*256*32 u32, 128 B cells)
    //   cnts      32,768,000    512,000 B (1000*256 u16, fully overwritten)
    //   xh        33,280,000  9,600,000 B (bf16, monolithic 192 B rows)
    //   Wfrag     42,880,000     49,152 B
    char* ws = (char*)d_ws;
    unsigned* binbuf = (unsigned*)ws;
    u16*      cnts   = (u16*)(ws + 32768000);
    u16*      xh     = (u16*)(ws + 33280000);
    u16*      Wfrag  = (u16*)(ws + 42880000);

    {
        dim3 grid(PART_BLOCKS + CONV_BLOCKS + WCONV_BLOCKS);   // 2612
        sage_part_conv<<<grid, 256, 0, stream>>>(src, dst, x, Wl, Wr,
                                                 cnts, binbuf, xh, Wfrag);
    }
    {
        dim3 grid(AG_BLOCKS);                                  // 1000
        sage_agg_gemm<<<grid, 512, 0, stream>>>(xh, cnts, binbuf,
                                                Wfrag, bl, out);
    }
}